// Round 1
// baseline (699.505 us; speedup 1.0000x reference)
//
#include <hip/hip_runtime.h>
#include <hip/hip_bf16.h>

// GCN: 2x GCNConv(64->64, relu) + FC(64->12)
// N_NODES=50000, N_EDGES=800000. All math f32.
//
// Pipeline (all on `stream`, graph-capture safe):
//  1. init:        deg[i]=1 (self loop), counts[i]=0
//  2. edge_count:  atomicAdd deg[dst]+=ew, counts[dst]+=1
//  3. dinv:        deg[i] = rsqrt(deg[i])   (deg>=1 always)
//  4-6. 3-kernel exclusive scan of counts -> rowstart, cursor
//  7. fill_csr:    bucket edges by dst: es[pos]=src, enorm[pos]=dinv[s]*w*dinv[d]
//  8. gemm64  x@W1 -> bufA
//  9. aggregate bufA -> bufB   (wave-per-node gather, +bias, relu)
// 10. gemm64  bufB@W2 -> bufA
// 11. aggregate bufA -> bufB
// 12. gemm_fc bufB@Wfc + bfc -> d_out

#define N_FEAT 64
#define OUT_F  12

__global__ void k_init(float* deg, int* counts, int n) {
    int i = blockIdx.x * 256 + threadIdx.x;
    if (i < n) { deg[i] = 1.0f; counts[i] = 0; }
}

__global__ void k_edge_count(const int* __restrict__ idx, const float* __restrict__ ew,
                             float* deg, int* counts, int n_edges) {
    int e = blockIdx.x * 256 + threadIdx.x;
    if (e >= n_edges) return;
    int d = idx[n_edges + e];
    atomicAdd(&deg[d], ew[e]);
    atomicAdd(&counts[d], 1);
}

__global__ void k_dinv(float* deg, int n) {
    int i = blockIdx.x * 256 + threadIdx.x;
    if (i < n) deg[i] = rsqrtf(deg[i]);   // deg >= 1 (self loop), no zero guard needed
}

// ---- 3-kernel exclusive scan over counts[n] (n <= 256*256) ----
__global__ void k_scan_bsum(const int* __restrict__ counts, int* bsum, int n) {
    __shared__ int sd[256];
    int i = blockIdx.x * 256 + threadIdx.x;
    sd[threadIdx.x] = (i < n) ? counts[i] : 0;
    __syncthreads();
    for (int s = 128; s > 0; s >>= 1) {
        if (threadIdx.x < s) sd[threadIdx.x] += sd[threadIdx.x + s];
        __syncthreads();
    }
    if (threadIdx.x == 0) bsum[blockIdx.x] = sd[0];
}

__global__ void k_scan_top(int* bsum, int nb) {   // single block, nb <= 256
    __shared__ int sd[256];
    int t = threadIdx.x;
    int v = (t < nb) ? bsum[t] : 0;
    sd[t] = v;
    __syncthreads();
    for (int off = 1; off < 256; off <<= 1) {
        int u = (t >= off) ? sd[t - off] : 0;
        __syncthreads();
        sd[t] += u;
        __syncthreads();
    }
    if (t < nb) bsum[t] = sd[t] - v;   // exclusive
}

__global__ void k_scan_apply(const int* __restrict__ counts, const int* __restrict__ bsum,
                             int* rowstart, int* cursor, int n) {
    __shared__ int sd[256];
    int t = threadIdx.x;
    int i = blockIdx.x * 256 + t;
    int v = (i < n) ? counts[i] : 0;
    sd[t] = v;
    __syncthreads();
    for (int off = 1; off < 256; off <<= 1) {
        int u = (t >= off) ? sd[t - off] : 0;
        __syncthreads();
        sd[t] += u;
        __syncthreads();
    }
    if (i < n) {
        int rs = bsum[blockIdx.x] + (sd[t] - v);
        rowstart[i] = rs;
        cursor[i]   = rs;
    }
}

__global__ void k_fill_csr(const int* __restrict__ idx, const float* __restrict__ ew,
                           const float* __restrict__ dinv, int* cursor,
                           int* es, float* enorm, int n_edges) {
    int e = blockIdx.x * 256 + threadIdx.x;
    if (e >= n_edges) return;
    int s = idx[e];
    int d = idx[n_edges + e];
    float w = ew[e];
    int pos = atomicAdd(&cursor[d], 1);
    es[pos]    = s;
    enorm[pos] = dinv[s] * w * dinv[d];
}

// Y[n,64] = X[n,64] @ W[64,64]; 16 rows/block, 256 threads.
__global__ void k_gemm64(const float* __restrict__ X, const float* __restrict__ W,
                         float* __restrict__ Y, int n_rows) {
    __shared__ float Ws[64 * 64];
    __shared__ float Xs[16 * 64];
    int t = threadIdx.x;
    for (int i = t; i < 4096; i += 256) Ws[i] = W[i];
    int row0 = blockIdx.x * 16;
    for (int i = t; i < 1024; i += 256) {
        int r = i >> 6, c = i & 63;
        int gr = row0 + r;
        Xs[i] = (gr < n_rows) ? X[gr * 64 + c] : 0.0f;
    }
    __syncthreads();
    int tx = t & 63;   // output feature (wave-contiguous -> conflict-free Ws reads)
    int ty = t >> 6;   // 0..3 (constant per wave -> Xs reads broadcast)
    float acc[4] = {0.f, 0.f, 0.f, 0.f};
    for (int k = 0; k < 64; k++) {
        float w = Ws[k * 64 + tx];
#pragma unroll
        for (int rr = 0; rr < 4; rr++) acc[rr] += Xs[(ty + rr * 4) * 64 + k] * w;
    }
#pragma unroll
    for (int rr = 0; rr < 4; rr++) {
        int gr = row0 + ty + rr * 4;
        if (gr < n_rows) Y[gr * 64 + tx] = acc[rr];
    }
}

// Wave-per-node gather aggregation: lane = feature.
// hout[i] = relu( dinv[i]^2 * hl[i] + sum_e enorm[e]*hl[es[e]] + bias )
__global__ void k_aggregate(const float* __restrict__ hl, const int* __restrict__ rowstart,
                            const int* __restrict__ counts, const int* __restrict__ es,
                            const float* __restrict__ enorm, const float* __restrict__ dinv,
                            const float* __restrict__ bias, float* __restrict__ hout,
                            int n_nodes) {
    int node = blockIdx.x * 4 + (threadIdx.x >> 6);
    int lane = threadIdx.x & 63;
    if (node >= n_nodes) return;
    float di  = dinv[node];
    float acc = hl[node * N_FEAT + lane] * (di * di);
    int start = rowstart[node];
    int cnt   = counts[node];
    for (int k = 0; k < cnt; k++) {
        int e = start + k;
        acc += enorm[e] * hl[es[e] * N_FEAT + lane];
    }
    acc += bias[lane];
    hout[node * N_FEAT + lane] = fmaxf(acc, 0.0f);
}

// out[n,12] = H[n,64] @ Wfc[64,12] + bfc
__global__ void k_gemm_fc(const float* __restrict__ H, const float* __restrict__ W,
                          const float* __restrict__ b, float* __restrict__ out,
                          int n_rows) {
    __shared__ float Ws[64 * OUT_F];
    __shared__ float bs[OUT_F];
    int t = threadIdx.x;
    for (int i = t; i < 64 * OUT_F; i += 256) Ws[i] = W[i];
    if (t < OUT_F) bs[t] = b[t];
    __syncthreads();
    int gid = blockIdx.x * 256 + t;
    if (gid >= n_rows * OUT_F) return;
    int r = gid / OUT_F;
    int c = gid - r * OUT_F;
    const float* hr = H + r * 64;
    float acc = 0.0f;
#pragma unroll
    for (int k = 0; k < 64; k++) acc += hr[k] * Ws[k * OUT_F + c];
    out[gid] = acc + bs[c];
}

extern "C" void kernel_launch(void* const* d_in, const int* in_sizes, int n_in,
                              void* d_out, int out_size, void* d_ws, size_t ws_size,
                              hipStream_t stream) {
    const float* x    = (const float*)d_in[0];
    const int*   idx  = (const int*)d_in[1];   // [2, E]; harness converts ints to int32
    const float* ew   = (const float*)d_in[2];
    const float* W1   = (const float*)d_in[3];
    const float* b1   = (const float*)d_in[4];
    const float* W2   = (const float*)d_in[5];
    const float* b2   = (const float*)d_in[6];
    const float* Wfc  = (const float*)d_in[7];
    const float* bfc  = (const float*)d_in[8];
    float* out = (float*)d_out;

    const int n_nodes = in_sizes[0] / N_FEAT;     // 50000
    const int n_edges = in_sizes[2];              // 800000 (edge_attr count)

    // workspace layout (f32 words)
    float* ws = (float*)d_ws;
    float* deg      = ws;                         // 50000 (becomes dinv in place)
    int*   counts   = (int*)(ws + 50016);         // 50000
    int*   rowstart = (int*)(ws + 100032);        // 50000
    int*   cursor   = (int*)(ws + 150048);        // 50000
    int*   bsum     = (int*)(ws + 200064);        // 256
    int*   es       = (int*)(ws + 200320);        // 800000
    float* enorm    = ws + 1000320;               // 800000
    float* bufA     = ws + 1800320;               // 3200000
    float* bufB     = ws + 5000320;               // 3200000
    // total: 8200320 words = 32.8 MB

    const int gN  = (n_nodes + 255) / 256;        // 196
    const int gE  = (n_edges + 255) / 256;        // 3125
    const int gG  = (n_nodes + 15) / 16;          // 3125 (gemm64)
    const int gA  = (n_nodes + 3) / 4;            // 12500 (aggregate)
    const int gFC = (n_nodes * OUT_F + 255) / 256;

    k_init<<<gN, 256, 0, stream>>>(deg, counts, n_nodes);
    k_edge_count<<<gE, 256, 0, stream>>>(idx, ew, deg, counts, n_edges);
    k_dinv<<<gN, 256, 0, stream>>>(deg, n_nodes);
    k_scan_bsum<<<gN, 256, 0, stream>>>(counts, bsum, n_nodes);
    k_scan_top<<<1, 256, 0, stream>>>(bsum, gN);
    k_scan_apply<<<gN, 256, 0, stream>>>(counts, bsum, rowstart, cursor, n_nodes);
    k_fill_csr<<<gE, 256, 0, stream>>>(idx, ew, deg, cursor, es, enorm, n_edges);

    k_gemm64<<<gG, 256, 0, stream>>>(x, W1, bufA, n_nodes);
    k_aggregate<<<gA, 256, 0, stream>>>(bufA, rowstart, counts, es, enorm, deg, b1, bufB, n_nodes);
    k_gemm64<<<gG, 256, 0, stream>>>(bufB, W2, bufA, n_nodes);
    k_aggregate<<<gA, 256, 0, stream>>>(bufA, rowstart, counts, es, enorm, deg, b2, bufB, n_nodes);
    k_gemm_fc<<<gFC, 256, 0, stream>>>(bufB, Wfc, bfc, out, n_nodes);
}

// Round 2
// 619.495 us; speedup vs baseline: 1.1292x; 1.1292x over previous
//
#include <hip/hip_runtime.h>
#include <hip/hip_bf16.h>

// GCN: 2x GCNConv(64->64, relu) + FC(64->12)
// N_NODES=50000, N_EDGES=800000.
//
// R1 changes:
//  - gemm64 writes bf16 (halves the aggregate gather bytes: 256 B -> 128 B per edge)
//  - aggregate gathers bf16, accumulates f32, writes f32
//  - float4-vectorized staging loads in gemm64
//  - unroll-by-2 aggregate inner loop (more outstanding gathers)

#define N_FEAT 64
#define OUT_F  12

__global__ void k_init(float* deg, int* counts, int n) {
    int i = blockIdx.x * 256 + threadIdx.x;
    if (i < n) { deg[i] = 1.0f; counts[i] = 0; }
}

__global__ void k_edge_count(const int* __restrict__ idx, const float* __restrict__ ew,
                             float* deg, int* counts, int n_edges) {
    int e = blockIdx.x * 256 + threadIdx.x;
    if (e >= n_edges) return;
    int d = idx[n_edges + e];
    atomicAdd(&deg[d], ew[e]);
    atomicAdd(&counts[d], 1);
}

__global__ void k_dinv(float* deg, int n) {
    int i = blockIdx.x * 256 + threadIdx.x;
    if (i < n) deg[i] = rsqrtf(deg[i]);   // deg >= 1 (self loop)
}

// ---- 3-kernel exclusive scan over counts[n] ----
__global__ void k_scan_bsum(const int* __restrict__ counts, int* bsum, int n) {
    __shared__ int sd[256];
    int i = blockIdx.x * 256 + threadIdx.x;
    sd[threadIdx.x] = (i < n) ? counts[i] : 0;
    __syncthreads();
    for (int s = 128; s > 0; s >>= 1) {
        if (threadIdx.x < s) sd[threadIdx.x] += sd[threadIdx.x + s];
        __syncthreads();
    }
    if (threadIdx.x == 0) bsum[blockIdx.x] = sd[0];
}

__global__ void k_scan_top(int* bsum, int nb) {   // single block, nb <= 256
    __shared__ int sd[256];
    int t = threadIdx.x;
    int v = (t < nb) ? bsum[t] : 0;
    sd[t] = v;
    __syncthreads();
    for (int off = 1; off < 256; off <<= 1) {
        int u = (t >= off) ? sd[t - off] : 0;
        __syncthreads();
        sd[t] += u;
        __syncthreads();
    }
    if (t < nb) bsum[t] = sd[t] - v;   // exclusive
}

__global__ void k_scan_apply(const int* __restrict__ counts, const int* __restrict__ bsum,
                             int* rowstart, int* cursor, int n) {
    __shared__ int sd[256];
    int t = threadIdx.x;
    int i = blockIdx.x * 256 + t;
    int v = (i < n) ? counts[i] : 0;
    sd[t] = v;
    __syncthreads();
    for (int off = 1; off < 256; off <<= 1) {
        int u = (t >= off) ? sd[t - off] : 0;
        __syncthreads();
        sd[t] += u;
        __syncthreads();
    }
    if (i < n) {
        int rs = bsum[blockIdx.x] + (sd[t] - v);
        rowstart[i] = rs;
        cursor[i]   = rs;
    }
}

__global__ void k_fill_csr(const int* __restrict__ idx, const float* __restrict__ ew,
                           const float* __restrict__ dinv, int* cursor,
                           int* es, float* enorm, int n_edges) {
    int e = blockIdx.x * 256 + threadIdx.x;
    if (e >= n_edges) return;
    int s = idx[e];
    int d = idx[n_edges + e];
    float w = ew[e];
    int pos = atomicAdd(&cursor[d], 1);
    es[pos]    = s;
    enorm[pos] = dinv[s] * w * dinv[d];
}

// Y[n,64](bf16) = X[n,64](f32) @ W[64,64](f32); 16 rows/block, 256 threads.
__global__ void k_gemm64_bf16(const float* __restrict__ X, const float* __restrict__ W,
                              __hip_bfloat16* __restrict__ Y, int n_rows) {
    __shared__ float Ws[64 * 64];
    __shared__ float Xs[16 * 64];
    int t = threadIdx.x;
    // W: 1024 float4
    {
        const float4* W4 = (const float4*)W;
        float4* Ws4 = (float4*)Ws;
        for (int i = t; i < 1024; i += 256) Ws4[i] = W4[i];
    }
    int row0 = blockIdx.x * 16;
    {
        // 256 float4 = 16 rows x 16 float4; thread t loads float4 #t
        int r = t >> 4, c4 = t & 15;
        int gr = row0 + r;
        float4 v = make_float4(0.f, 0.f, 0.f, 0.f);
        if (gr < n_rows) v = ((const float4*)X)[gr * 16 + c4];
        ((float4*)Xs)[t] = v;
    }
    __syncthreads();
    int tx = t & 63;   // output feature
    int ty = t >> 6;   // 0..3
    float acc[4] = {0.f, 0.f, 0.f, 0.f};
    for (int k = 0; k < 64; k++) {
        float w = Ws[k * 64 + tx];
#pragma unroll
        for (int rr = 0; rr < 4; rr++) acc[rr] += Xs[(ty + rr * 4) * 64 + k] * w;
    }
#pragma unroll
    for (int rr = 0; rr < 4; rr++) {
        int gr = row0 + ty + rr * 4;
        if (gr < n_rows) Y[gr * 64 + tx] = __float2bfloat16(acc[rr]);
    }
}

// Wave-per-node gather aggregation: lane = feature. hl is bf16.
// hout[i] = relu( dinv[i]^2 * hl[i] + sum_e enorm[e]*hl[es[e]] + bias )
__global__ void k_aggregate(const __hip_bfloat16* __restrict__ hl,
                            const int* __restrict__ rowstart,
                            const int* __restrict__ counts, const int* __restrict__ es,
                            const float* __restrict__ enorm, const float* __restrict__ dinv,
                            const float* __restrict__ bias, float* __restrict__ hout,
                            int n_nodes) {
    int node = blockIdx.x * 4 + (threadIdx.x >> 6);
    int lane = threadIdx.x & 63;
    if (node >= n_nodes) return;
    float di  = dinv[node];
    float acc = __bfloat162float(hl[node * N_FEAT + lane]) * (di * di);
    int start = rowstart[node];
    int cnt   = counts[node];
    int k = 0;
    for (; k + 1 < cnt; k += 2) {
        int e0 = es[start + k], e1 = es[start + k + 1];
        float c0 = enorm[start + k], c1 = enorm[start + k + 1];
        float v0 = __bfloat162float(hl[e0 * N_FEAT + lane]);
        float v1 = __bfloat162float(hl[e1 * N_FEAT + lane]);
        acc += c0 * v0;
        acc += c1 * v1;
    }
    if (k < cnt) {
        int e0 = es[start + k];
        acc += enorm[start + k] * __bfloat162float(hl[e0 * N_FEAT + lane]);
    }
    acc += bias[lane];
    hout[node * N_FEAT + lane] = fmaxf(acc, 0.0f);
}

// out[n,12] = H[n,64] @ Wfc[64,12] + bfc
__global__ void k_gemm_fc(const float* __restrict__ H, const float* __restrict__ W,
                          const float* __restrict__ b, float* __restrict__ out,
                          int n_rows) {
    __shared__ float Ws[64 * OUT_F];
    __shared__ float bs[OUT_F];
    int t = threadIdx.x;
    for (int i = t; i < 64 * OUT_F; i += 256) Ws[i] = W[i];
    if (t < OUT_F) bs[t] = b[t];
    __syncthreads();
    int gid = blockIdx.x * 256 + t;
    if (gid >= n_rows * OUT_F) return;
    int r = gid / OUT_F;
    int c = gid - r * OUT_F;
    const float* hr = H + r * 64;
    float acc = 0.0f;
#pragma unroll
    for (int k = 0; k < 64; k++) acc += hr[k] * Ws[k * OUT_F + c];
    out[gid] = acc + bs[c];
}

extern "C" void kernel_launch(void* const* d_in, const int* in_sizes, int n_in,
                              void* d_out, int out_size, void* d_ws, size_t ws_size,
                              hipStream_t stream) {
    const float* x    = (const float*)d_in[0];
    const int*   idx  = (const int*)d_in[1];   // [2, E] as int32
    const float* ew   = (const float*)d_in[2];
    const float* W1   = (const float*)d_in[3];
    const float* b1   = (const float*)d_in[4];
    const float* W2   = (const float*)d_in[5];
    const float* b2   = (const float*)d_in[6];
    const float* Wfc  = (const float*)d_in[7];
    const float* bfc  = (const float*)d_in[8];
    float* out = (float*)d_out;

    const int n_nodes = in_sizes[0] / N_FEAT;     // 50000
    const int n_edges = in_sizes[2];              // 800000

    // workspace layout (f32 words)
    float* ws = (float*)d_ws;
    float* deg      = ws;                         // 50000 (becomes dinv in place)
    int*   counts   = (int*)(ws + 50016);         // 50000
    int*   rowstart = (int*)(ws + 100032);        // 50000
    int*   cursor   = (int*)(ws + 150048);        // 50000
    int*   bsum     = (int*)(ws + 200064);        // 256
    int*   es       = (int*)(ws + 200320);        // 800000
    float* enorm    = ws + 1000320;               // 800000
    __hip_bfloat16* hlbf = (__hip_bfloat16*)(ws + 1800320);  // 3.2M bf16 = 1.6M words
    float* hbuf     = ws + 3400320;               // 3.2M f32 (aggregate output)
    // total: 6600320 words = 26.4 MB

    const int gN  = (n_nodes + 255) / 256;
    const int gE  = (n_edges + 255) / 256;
    const int gG  = (n_nodes + 15) / 16;
    const int gA  = (n_nodes + 3) / 4;
    const int gFC = (n_nodes * OUT_F + 255) / 256;

    k_init<<<gN, 256, 0, stream>>>(deg, counts, n_nodes);
    k_edge_count<<<gE, 256, 0, stream>>>(idx, ew, deg, counts, n_edges);
    k_dinv<<<gN, 256, 0, stream>>>(deg, n_nodes);
    k_scan_bsum<<<gN, 256, 0, stream>>>(counts, bsum, n_nodes);
    k_scan_top<<<1, 256, 0, stream>>>(bsum, gN);
    k_scan_apply<<<gN, 256, 0, stream>>>(counts, bsum, rowstart, cursor, n_nodes);
    k_fill_csr<<<gE, 256, 0, stream>>>(idx, ew, deg, cursor, es, enorm, n_edges);

    k_gemm64_bf16<<<gG, 256, 0, stream>>>(x, W1, hlbf, n_nodes);
    k_aggregate<<<gA, 256, 0, stream>>>(hlbf, rowstart, counts, es, enorm, deg, b1, hbuf, n_nodes);
    k_gemm64_bf16<<<gG, 256, 0, stream>>>(hbuf, W2, hlbf, n_nodes);
    k_aggregate<<<gA, 256, 0, stream>>>(hlbf, rowstart, counts, es, enorm, deg, b2, hbuf, n_nodes);
    k_gemm_fc<<<gFC, 256, 0, stream>>>(hbuf, Wfc, bfc, out, n_nodes);
}